// Round 6
// baseline (366.821 us; speedup 1.0000x reference)
//
#include <hip/hip_runtime.h>
#include <hip/hip_bf16.h>
#include <math.h>

#define Bb   64
#define Nn   256
#define Mm   16
#define ONF  92
#define OEF  41
#define NF   128
#define EF   64
#define KDIM 320   // 2*NF + EF
#define ODIM 256   // 2*NF
#define FINAL 128

typedef __attribute__((ext_vector_type(8))) short short8;
typedef __attribute__((ext_vector_type(4))) float f32x4;

__device__ __forceinline__ float sigmoidf_(float x) {
    float e = __expf(-x);
    return __builtin_amdgcn_rcpf(1.0f + e);
}
__device__ __forceinline__ float softplusf_(float x) {
    return fmaxf(x, 0.0f) + __logf(1.0f + __expf(-fabsf(x)));
}
__device__ __forceinline__ __hip_bfloat16 to_bf16(float x) { return __float2bfloat16(x); }

// ---------- tiny prep kernels ----------
// in: [O][I] -> out: [I][O]  (f32) — fallback conv path only
__global__ void k_transpose(const float* __restrict__ in, float* __restrict__ out, int O, int I)
{
    int t = blockIdx.x * 256 + threadIdx.x;
    if (t < O * I) {
        int o = t / I, i = t - o * I;
        out[i * O + o] = in[t];
    }
}

// W [ODIM][KDIM] f32 -> bf16 in MFMA-B-fragment order (conv weights, K exact)
__global__ void k_wswz(const float* __restrict__ in, __hip_bfloat16* __restrict__ out)
{
    int t = blockIdx.x * 256 + threadIdx.x;
    if (t < ODIM * KDIM) {
        int n = t / KDIM, k = t - n * KDIM;
        int tile = n >> 4, ln16 = n & 15;
        int k0 = k >> 5, q = (k >> 3) & 3, j = k & 7;
        out[(size_t)(((tile * 10 + k0) << 6) + (q << 4) + ln16) * 8 + j] = to_bf16(in[t]);
    }
}

// W [O][I] f32 -> bf16 B-fragment order with K padded to K0*32 (zeros).
__global__ void k_wswz_pad(const float* __restrict__ in, __hip_bfloat16* __restrict__ out,
                           int O, int I, int K0)
{
    int t = blockIdx.x * 256 + threadIdx.x;
    int total = (O >> 4) * K0 * 512;
    if (t < total) {
        int j = t & 7;
        int u = t >> 3;
        int lane = u & 63;
        int ln16 = lane & 15, q = lane >> 4;
        int v = u >> 6;
        int k0 = v % K0, tile = v / K0;
        int n = tile * 16 + ln16, k = k0 * 32 + q * 8 + j;
        out[t] = (k < I) ? to_bf16(in[n * I + k]) : to_bf16(0.0f);
    }
}

// DA = sigmoid(w*dis+b) in bf16 A-fragment order
__global__ void k_da(const float* __restrict__ dis, const float* __restrict__ pw,
                     const float* __restrict__ pb, __hip_bfloat16* __restrict__ DAf)
{
    int t = blockIdx.x * 256 + threadIdx.x;
    if (t < Nn * Nn) {
        int i = t >> 8, jx = t & 255;
        float v = sigmoidf_(fmaf(*pw, dis[t], *pb));
        int itile = i >> 4, ln16 = i & 15;
        int k0 = jx >> 5, q = (jx >> 3) & 3, jj = jx & 7;
        DAf[(size_t)((((itile * 8 + k0) << 6) + (q << 4) + ln16)) * 8 + jj] = to_bf16(v);
    }
}

// ---------- generic MFMA embed: Y[r][c] = X[r][:KIN] . W[c][:KIN] + bias[c] ----------
// Flat float4 staging; epilogue via LDS transpose -> coalesced uint4 stores.
template<int KIN, int K0, int NCOLS>
__global__ __launch_bounds__(256) void k_emb(
    const float* __restrict__ X, const __hip_bfloat16* __restrict__ Bswz,
    const float* __restrict__ bias, __hip_bfloat16* __restrict__ Y)
{
    constexpr int KP = K0 * 32;
    constexpr int TPW = NCOLS / 64;        // col-tiles per wave
    constexpr int OLD = NCOLS + 24;        // out-staging stride: rows stay 16B-aligned
    __shared__ __align__(16) __hip_bfloat16 A_s[4 * K0 * 512];
    __shared__ __align__(16) __hip_bfloat16 O_s[64 * OLD];

    const int row0 = blockIdx.x * 64;
    const int t = threadIdx.x;

    // flat float4 staging of X rows [row0, row0+64)
    {
        const float4* Xb = (const float4*)(X + (size_t)row0 * KIN);
        constexpr int NV = (64 * KIN) / 4;
        for (int c = t; c < NV; c += 256) {
            float4 v = Xb[c];
            int flat = c * 4;
            #pragma unroll
            for (int e = 0; e < 4; e++) {
                int f = flat + e;
                int row = f / KIN, k = f - row * KIN;
                int mt = row >> 4, ln16 = row & 15;
                int k0 = k >> 5, q = (k >> 3) & 3, j = k & 7;
                float vv = (e == 0) ? v.x : (e == 1) ? v.y : (e == 2) ? v.z : v.w;
                A_s[(((mt * K0 + k0) << 6) + (q << 4) + ln16) * 8 + j] = to_bf16(vv);
            }
        }
        constexpr int PAD = KP - KIN;
        for (int c = t; c < 64 * PAD; c += 256) {
            int row = c / PAD, k = KIN + (c - row * PAD);
            int mt = row >> 4, ln16 = row & 15;
            int k0 = k >> 5, q = (k >> 3) & 3, j = k & 7;
            A_s[(((mt * K0 + k0) << 6) + (q << 4) + ln16) * 8 + j] = to_bf16(0.0f);
        }
    }
    __syncthreads();

    const int wv = t >> 6, lane = t & 63;
    const int q = lane >> 4, ln16 = lane & 15;

    f32x4 acc[4][TPW];
    #pragma unroll
    for (int p = 0; p < TPW; p++) {
        float bv = bias[(wv * TPW + p) * 16 + ln16];
        #pragma unroll
        for (int mt = 0; mt < 4; mt++) acc[mt][p] = (f32x4){bv, bv, bv, bv};
    }

    short8 bw[TPW][K0];
    #pragma unroll
    for (int p = 0; p < TPW; p++)
        #pragma unroll
        for (int k0 = 0; k0 < K0; k0++)
            bw[p][k0] = *(const short8*)(Bswz + ((size_t)((wv * TPW + p) * K0 + k0) << 9) + (lane << 3));

    #pragma unroll
    for (int k0 = 0; k0 < K0; k0++) {
        short8 af[4];
        #pragma unroll
        for (int mt = 0; mt < 4; mt++)
            af[mt] = *(const short8*)(A_s + (((mt * K0 + k0) << 6) + lane) * 8);
        #pragma unroll
        for (int mt = 0; mt < 4; mt++)
            #pragma unroll
            for (int p = 0; p < TPW; p++)
                acc[mt][p] = __builtin_amdgcn_mfma_f32_16x16x32_bf16(af[mt], bw[p][k0], acc[mt][p], 0, 0, 0);
    }

    // epilogue: LDS transpose then coalesced stores
    #pragma unroll
    for (int mt = 0; mt < 4; mt++)
        #pragma unroll
        for (int p = 0; p < TPW; p++) {
            int col = (wv * TPW + p) * 16 + ln16;
            #pragma unroll
            for (int r = 0; r < 4; r++)
                O_s[(mt * 16 + q * 4 + r) * OLD + col] = to_bf16(acc[mt][p][r]);
        }
    __syncthreads();
    constexpr int CH = NCOLS / 8;
    for (int c = t; c < 64 * CH; c += 256) {
        int row = c / CH, ch = c - row * CH;
        *(uint4*)(Y + (size_t)(row0 + row) * NCOLS + ch * 8) =
            *(const uint4*)(O_s + row * OLD + ch * 8);
    }
}

// ---------- conv layer: MFMA, fragment-order A in LDS, LDS = exactly 40 KB ----------
template<bool PRECOMP>
__global__ __launch_bounds__(256, 4) void k_conv_mfma(
    const __hip_bfloat16* __restrict__ nf_in,   // [B*N][NF] bf16
    const float* __restrict__ edge_fea,         // [B*N*M][OEF] f32  (PRECOMP=false)
    const __hip_bfloat16* __restrict__ ef_bf,   // [B*N*M][EF] bf16  (PRECOMP=true)
    const int*   __restrict__ eidx,             // [B*N][M]
    const float* __restrict__ WeT,              // [OEF][EF] f32     (PRECOMP=false)
    const float* __restrict__ be,               // [EF]              (PRECOMP=false)
    const __hip_bfloat16* __restrict__ Wb,      // swizzled [16][10][64][8] bf16
    const float* __restrict__ bias,             // [ODIM]
    const float* __restrict__ palpha,
    __hip_bfloat16* __restrict__ nf_out)        // [B*N][NF] bf16
{
    __shared__ __align__(16) __hip_bfloat16 A_s[40 * 512];   // 40960 B -> 4 blocks/CU

    const int node0 = blockIdx.x * 4;
    const int b = node0 >> 8;
    const int t = threadIdx.x;
    const int wv = t >> 6, lane = t & 63;
    const int q = lane >> 4, ln16 = lane & 15;

    // idx without LDS: per-lane reloads (L1 broadcast) + 64-bit ballot mask
    const int row = (wv << 4) + ln16;                 // this lane's A-tile row
    const int myidx = eidx[node0 * Mm + row];
    const unsigned long long mball = __ballot(eidx[node0 * Mm + lane] >= 0);

    // stage A (fragment order, conflict-free: base + lane*16)
    {
        int j = myidx < 0 ? 0 : myidx;
        const __hip_bfloat16* selfp = nf_in + (size_t)(node0 + wv) * NF;
        const __hip_bfloat16* gathp = nf_in + (size_t)((b << 8) + j) * NF;
        #pragma unroll
        for (int k0 = 0; k0 < 4; k0++)
            *(uint4*)(A_s + ((wv * 10 + k0) * 64 + lane) * 8) =
                *(const uint4*)(selfp + k0 * 32 + q * 8);
        #pragma unroll
        for (int k0 = 0; k0 < 4; k0++)
            *(uint4*)(A_s + ((wv * 10 + 4 + k0) * 64 + lane) * 8) =
                *(const uint4*)(gathp + k0 * 32 + q * 8);
        if (PRECOMP) {
            const __hip_bfloat16* efp = ef_bf + (size_t)((node0 << 4) + row) * EF;
            #pragma unroll
            for (int k0 = 0; k0 < 2; k0++)
                *(uint4*)(A_s + ((wv * 10 + 8 + k0) * 64 + lane) * 8) =
                    *(const uint4*)(efp + k0 * 32 + q * 8);
        } else {
            for (int c = t; c < 64 * EF; c += 256) {
                int rr = c >> 6, col = c & 63;
                float a = be[col];
                const float* er = edge_fea + (size_t)(node0 * Mm + rr) * OEF;
                #pragma unroll
                for (int i = 0; i < OEF; i++) a = fmaf(er[i], WeT[i * EF + col], a);
                int mt = rr >> 4, l16 = rr & 15;
                int k0 = 8 + (col >> 5), qq = (col >> 3) & 3, jj = col & 7;
                A_s[((mt * 10 + k0) * 64 + qq * 16 + l16) * 8 + jj] = to_bf16(a);
            }
        }
    }
    __syncthreads();

    f32x4 accF[4][2], accC[4][2];
    #pragma unroll
    for (int p = 0; p < 2; p++) {
        int colF = (2 * wv + p) * 16 + ln16;
        float bF = bias[colF], bC = bias[colF + NF];
        #pragma unroll
        for (int mt = 0; mt < 4; mt++) {
            accF[mt][p] = (f32x4){bF, bF, bF, bF};
            accC[mt][p] = (f32x4){bC, bC, bC, bC};
        }
    }

    const __hip_bfloat16* WF0 = Wb + ((size_t)(2 * wv) * 5120) + (lane << 3);
    const __hip_bfloat16* WF1 = WF0 + 5120;
    const __hip_bfloat16* WC0 = WF0 + 8 * 5120;
    const __hip_bfloat16* WC1 = WC0 + 5120;

    short8 cF0 = *(const short8*)WF0;
    short8 cF1 = *(const short8*)WF1;
    short8 cC0 = *(const short8*)WC0;
    short8 cC1 = *(const short8*)WC1;

    #pragma unroll
    for (int k0 = 0; k0 < 10; k0++) {
        short8 nF0, nF1, nC0, nC1;
        if (k0 < 9) {
            nF0 = *(const short8*)(WF0 + (k0 + 1) * 512);
            nF1 = *(const short8*)(WF1 + (k0 + 1) * 512);
            nC0 = *(const short8*)(WC0 + (k0 + 1) * 512);
            nC1 = *(const short8*)(WC1 + (k0 + 1) * 512);
        }
        short8 af[4];
        #pragma unroll
        for (int mt = 0; mt < 4; mt++)
            af[mt] = *(const short8*)(A_s + ((mt * 10 + k0) * 64 + lane) * 8);
        #pragma unroll
        for (int mt = 0; mt < 4; mt++) {
            accF[mt][0] = __builtin_amdgcn_mfma_f32_16x16x32_bf16(af[mt], cF0, accF[mt][0], 0, 0, 0);
            accF[mt][1] = __builtin_amdgcn_mfma_f32_16x16x32_bf16(af[mt], cF1, accF[mt][1], 0, 0, 0);
            accC[mt][0] = __builtin_amdgcn_mfma_f32_16x16x32_bf16(af[mt], cC0, accC[mt][0], 0, 0, 0);
            accC[mt][1] = __builtin_amdgcn_mfma_f32_16x16x32_bf16(af[mt], cC1, accC[mt][1], 0, 0, 0);
        }
        cF0 = nF0; cF1 = nF1; cC0 = nC0; cC1 = nC1;
    }

    // epilogue
    const float alpha = *palpha;
    #pragma unroll
    for (int mt = 0; mt < 4; mt++) {
        const int gnode = node0 + mt;
        #pragma unroll
        for (int p = 0; p < 2; p++) {
            float partial = 0.0f;
            #pragma unroll
            for (int r = 0; r < 4; r++) {
                bool msk = (mball >> (mt * 16 + q * 4 + r)) & 1ull;
                float f = sigmoidf_(accF[mt][p][r]);
                float c = softplusf_(accC[mt][p][r]);
                partial += msk ? f * c : 0.0f;
            }
            partial += __shfl_xor(partial, 16);
            partial += __shfl_xor(partial, 32);
            if (q == 0) {
                int col = (2 * wv + p) * 16 + ln16;
                float self = __bfloat162float(nf_in[(size_t)gnode * NF + col]);
                nf_out[(size_t)gnode * NF + col] = to_bf16(softplusf_(fmaf(alpha, self, partial)));
            }
        }
    }
}

// ---------- final linear (MFMA): out[:, :, 0:64] = nf3 @ Wf^T + bf ----------
__global__ __launch_bounds__(256) void k_final_mfma(
    const __hip_bfloat16* __restrict__ nf, const __hip_bfloat16* __restrict__ Wfb,
    const float* __restrict__ bfv, float* __restrict__ out,
    __hip_bfloat16* __restrict__ XT)
{
    __shared__ __align__(16) __hip_bfloat16 A_s[16 * 512];  // 16 KB
    const int node0 = blockIdx.x * 64;
    const int bloc = node0 >> 8;
    const int t = threadIdx.x;
    const int wv = t >> 6, lane = t & 63;
    const int q = lane >> 4, ln16 = lane & 15;

    const __hip_bfloat16* rowp = nf + (size_t)(node0 + (wv << 4) + ln16) * NF;
    #pragma unroll
    for (int k0 = 0; k0 < 4; k0++)
        *(uint4*)(A_s + ((wv * 4 + k0) * 64 + lane) * 8) =
            *(const uint4*)(rowp + k0 * 32 + q * 8);
    __syncthreads();

    short8 bw[4];
    #pragma unroll
    for (int k0 = 0; k0 < 4; k0++)
        bw[k0] = *(const short8*)(Wfb + ((size_t)(wv * 4 + k0) * 64 + lane) * 8);

    float bv = bfv[wv * 16 + ln16];
    f32x4 acc[4];
    #pragma unroll
    for (int mt = 0; mt < 4; mt++) acc[mt] = (f32x4){bv, bv, bv, bv};

    #pragma unroll
    for (int k0 = 0; k0 < 4; k0++) {
        short8 af[4];
        #pragma unroll
        for (int mt = 0; mt < 4; mt++)
            af[mt] = *(const short8*)(A_s + ((mt * 4 + k0) * 64 + lane) * 8);
        #pragma unroll
        for (int mt = 0; mt < 4; mt++)
            acc[mt] = __builtin_amdgcn_mfma_f32_16x16x32_bf16(af[mt], bw[k0], acc[mt], 0, 0, 0);
    }

    const int col = (wv << 4) + ln16;                 // 0..63
    #pragma unroll
    for (int mt = 0; mt < 4; mt++)
        #pragma unroll
        for (int r = 0; r < 4; r++) {
            int row = mt * 16 + q * 4 + r;            // 0..63
            float v = acc[mt][r];
            out[(size_t)(node0 + row) * FINAL + col] = v;
            XT[(size_t)(bloc * 64 + col) * 256 + (node0 & 255) + row] = to_bf16(v);
        }
}

// ---------- node1 (MFMA): out[:, :, 64:128] = DA @ nff per batch ----------
__global__ __launch_bounds__(256) void k_node1_mfma(
    const __hip_bfloat16* __restrict__ DAf,   // A-fragment order [16][8][64][8]
    const __hip_bfloat16* __restrict__ XT,    // [B][64 f][256 j] bf16
    float* __restrict__ out)
{
    __shared__ __align__(16) __hip_bfloat16 B_s[32 * 512];  // 32 KB
    const int blk = blockIdx.x;
    const int b = blk >> 2, i0 = (blk & 3) * 64;
    const int t = threadIdx.x;
    const int wv = t >> 6, lane = t & 63;
    const int q = lane >> 4, ln16 = lane & 15;

    const __hip_bfloat16* xrow = XT + (size_t)(b * 64 + (wv << 4) + ln16) * 256;
    #pragma unroll
    for (int k0 = 0; k0 < 8; k0++)
        *(uint4*)(B_s + ((wv * 8 + k0) * 64 + lane) * 8) =
            *(const uint4*)(xrow + k0 * 32 + q * 8);
    __syncthreads();

    f32x4 acc[4];
    #pragma unroll
    for (int mt = 0; mt < 4; mt++) acc[mt] = (f32x4){0.f, 0.f, 0.f, 0.f};

    #pragma unroll
    for (int k0 = 0; k0 < 8; k0++) {
        short8 bfr = *(const short8*)(B_s + ((wv * 8 + k0) * 64 + lane) * 8);
        short8 af[4];
        #pragma unroll
        for (int mt = 0; mt < 4; mt++)
            af[mt] = *(const short8*)(DAf + (size_t)(((i0 >> 4) + mt) * 8 + k0) * 512 + (lane << 3));
        #pragma unroll
        for (int mt = 0; mt < 4; mt++)
            acc[mt] = __builtin_amdgcn_mfma_f32_16x16x32_bf16(af[mt], bfr, acc[mt], 0, 0, 0);
    }

    #pragma unroll
    for (int mt = 0; mt < 4; mt++)
        #pragma unroll
        for (int r = 0; r < 4; r++) {
            int i = i0 + mt * 16 + q * 4 + r;
            out[(size_t)((b << 8) + i) * FINAL + 64 + (wv << 4) + ln16] = acc[mt][r];
        }
}

extern "C" void kernel_launch(void* const* d_in, const int* in_sizes, int n_in,
                              void* d_out, int out_size, void* d_ws, size_t ws_size,
                              hipStream_t stream)
{
    const float* node_fea = (const float*)d_in[0];
    const float* edge_fea = (const float*)d_in[1];
    const int*   eidx     = (const int*)  d_in[2];
    const float* dis      = (const float*)d_in[3];
    const float* Wn = (const float*)d_in[4];
    const float* bn = (const float*)d_in[5];
    const float* We = (const float*)d_in[6];
    const float* be = (const float*)d_in[7];
    const float* W1 = (const float*)d_in[8];
    const float* b1 = (const float*)d_in[9];
    const float* a1 = (const float*)d_in[10];
    const float* W2 = (const float*)d_in[11];
    const float* b2 = (const float*)d_in[12];
    const float* a2 = (const float*)d_in[13];
    const float* W3 = (const float*)d_in[14];
    const float* b3 = (const float*)d_in[15];
    const float* a3 = (const float*)d_in[16];
    const float* Wf = (const float*)d_in[17];
    const float* bf = (const float*)d_in[18];
    const float* DAw = (const float*)d_in[19];
    const float* DAb = (const float*)d_in[20];
    float* out = (float*)d_out;

    // workspace layout (bytes, 256-aligned blocks)
    char* base = (char*)d_ws;
    size_t off = 0;
    auto alloc = [&](size_t bytes) { char* p = base + off; off = (off + bytes + 255) & ~(size_t)255; return p; };
    __hip_bfloat16* nfA = (__hip_bfloat16*)alloc((size_t)Bb * Nn * NF * 2);
    __hip_bfloat16* nfB = (__hip_bfloat16*)alloc((size_t)Bb * Nn * NF * 2);
    __hip_bfloat16* W1b = (__hip_bfloat16*)alloc((size_t)ODIM * KDIM * 2);
    __hip_bfloat16* W2b = (__hip_bfloat16*)alloc((size_t)ODIM * KDIM * 2);
    __hip_bfloat16* W3b = (__hip_bfloat16*)alloc((size_t)ODIM * KDIM * 2);
    float* WeT = (float*)alloc((size_t)OEF * EF * 4);                               // fallback conv path
    __hip_bfloat16* DAf = (__hip_bfloat16*)alloc((size_t)Nn * Nn * 2);              // DA, A-frag order
    __hip_bfloat16* Wnb = (__hip_bfloat16*)alloc((size_t)(NF / 16) * 3 * 512 * 2);  // node embed B, K0=3
    __hip_bfloat16* Web = (__hip_bfloat16*)alloc((size_t)(EF / 16) * 2 * 512 * 2);  // edge embed B, K0=2
    __hip_bfloat16* Wfb = (__hip_bfloat16*)alloc((size_t)(64 / 16) * 4 * 512 * 2);  // final B, K0=4
    __hip_bfloat16* XT  = (__hip_bfloat16*)alloc((size_t)Bb * 64 * Nn * 2);         // nff^T per batch
    __hip_bfloat16* efb = (__hip_bfloat16*)alloc((size_t)Bb * Nn * Mm * EF * 2);    // 33.5 MB
    const bool precomp = (ws_size >= off);

    // prep
    hipLaunchKernelGGL(k_transpose, dim3((EF * OEF + 255) / 256), dim3(256), 0, stream, We, WeT, EF, OEF);
    hipLaunchKernelGGL(k_wswz, dim3((ODIM * KDIM + 255) / 256), dim3(256), 0, stream, W1, W1b);
    hipLaunchKernelGGL(k_wswz, dim3((ODIM * KDIM + 255) / 256), dim3(256), 0, stream, W2, W2b);
    hipLaunchKernelGGL(k_wswz, dim3((ODIM * KDIM + 255) / 256), dim3(256), 0, stream, W3, W3b);
    hipLaunchKernelGGL(k_wswz_pad, dim3(((NF / 16) * 3 * 512 + 255) / 256), dim3(256), 0, stream, Wn, Wnb, NF, ONF, 3);
    hipLaunchKernelGGL(k_wswz_pad, dim3(((EF / 16) * 2 * 512 + 255) / 256), dim3(256), 0, stream, We, Web, EF, OEF, 2);
    hipLaunchKernelGGL(k_wswz_pad, dim3(((64 / 16) * 4 * 512 + 255) / 256), dim3(256), 0, stream, Wf, Wfb, 64, NF, 4);
    hipLaunchKernelGGL(k_da, dim3((Nn * Nn + 255) / 256), dim3(256), 0, stream, dis, DAw, DAb, DAf);

    // embeds (MFMA)
    if (precomp)
        hipLaunchKernelGGL((k_emb<OEF, 2, EF>), dim3(Bb * Nn * Mm / 64), dim3(256), 0, stream,
                           edge_fea, Web, be, efb);
    hipLaunchKernelGGL((k_emb<ONF, 3, NF>), dim3(Bb * Nn / 64), dim3(256), 0, stream,
                       node_fea, Wnb, bn, nfA);

    if (precomp) {
        hipLaunchKernelGGL((k_conv_mfma<true>), dim3(Bb * Nn / 4), dim3(256), 0, stream,
                           nfA, edge_fea, efb, eidx, WeT, be, W1b, b1, a1, nfB);
        hipLaunchKernelGGL((k_conv_mfma<true>), dim3(Bb * Nn / 4), dim3(256), 0, stream,
                           nfB, edge_fea, efb, eidx, WeT, be, W2b, b2, a2, nfA);
        hipLaunchKernelGGL((k_conv_mfma<true>), dim3(Bb * Nn / 4), dim3(256), 0, stream,
                           nfA, edge_fea, efb, eidx, WeT, be, W3b, b3, a3, nfB);
    } else {
        hipLaunchKernelGGL((k_conv_mfma<false>), dim3(Bb * Nn / 4), dim3(256), 0, stream,
                           nfA, edge_fea, efb, eidx, WeT, be, W1b, b1, a1, nfB);
        hipLaunchKernelGGL((k_conv_mfma<false>), dim3(Bb * Nn / 4), dim3(256), 0, stream,
                           nfB, edge_fea, efb, eidx, WeT, be, W2b, b2, a2, nfA);
        hipLaunchKernelGGL((k_conv_mfma<false>), dim3(Bb * Nn / 4), dim3(256), 0, stream,
                           nfA, edge_fea, efb, eidx, WeT, be, W3b, b3, a3, nfB);
    }

    hipLaunchKernelGGL(k_final_mfma, dim3(Bb * Nn / 64), dim3(256), 0, stream, nfB, Wfb, bf, out, XT);
    hipLaunchKernelGGL(k_node1_mfma, dim3(Bb * 4), dim3(256), 0, stream, DAf, XT, out);
}

// Round 7
// 344.737 us; speedup vs baseline: 1.0641x; 1.0641x over previous
//
#include <hip/hip_runtime.h>
#include <hip/hip_bf16.h>
#include <math.h>

#define Bb   64
#define Nn   256
#define Mm   16
#define ONF  92
#define OEF  41
#define NF   128
#define EF   64
#define KDIM 320   // 2*NF + EF
#define ODIM 256   // 2*NF
#define FINAL 128
#define K0C  6     // conv K-chunks (K=192: gather 128 + edge 64)

typedef __attribute__((ext_vector_type(8))) short short8;
typedef __attribute__((ext_vector_type(4))) float f32x4;

__device__ __forceinline__ float sigmoidf_(float x) {
    float e = __expf(-x);
    return __builtin_amdgcn_rcpf(1.0f + e);
}
__device__ __forceinline__ float softplusf_(float x) {
    return fmaxf(x, 0.0f) + __logf(1.0f + __expf(-fabsf(x)));
}
__device__ __forceinline__ __hip_bfloat16 to_bf16(float x) { return __float2bfloat16(x); }

// ---------- tiny prep kernels ----------
// in: [O][I] -> out: [I][O]  (f32) — fallback conv path only
__global__ void k_transpose(const float* __restrict__ in, float* __restrict__ out, int O, int I)
{
    int t = blockIdx.x * 256 + threadIdx.x;
    if (t < O * I) {
        int o = t / I, i = t - o * I;
        out[i * O + o] = in[t];
    }
}

// Generic B-fragment swizzle: W rows n in [O], take K slice [koff, koff+Kuse) of
// row stride Itot, pad K to K0*32. dst: [tile(O/16)][k0(K0)][lane(64)][8] bf16.
__global__ void k_wswz2(const float* __restrict__ in, __hip_bfloat16* __restrict__ out,
                        int O, int Itot, int koff, int Kuse, int K0)
{
    int t = blockIdx.x * 256 + threadIdx.x;
    int total = (O >> 4) * K0 * 512;
    if (t < total) {
        int j = t & 7;
        int u = t >> 3;
        int lane = u & 63;
        int ln16 = lane & 15, q = lane >> 4;
        int v = u >> 6;
        int k0 = v % K0, tile = v / K0;
        int n = tile * 16 + ln16, k = k0 * 32 + q * 8 + j;
        out[t] = (k < Kuse) ? to_bf16(in[(size_t)n * Itot + koff + k]) : to_bf16(0.0f);
    }
}

// DA = sigmoid(w*dis+b) in bf16 A-fragment order
__global__ void k_da(const float* __restrict__ dis, const float* __restrict__ pw,
                     const float* __restrict__ pb, __hip_bfloat16* __restrict__ DAf)
{
    int t = blockIdx.x * 256 + threadIdx.x;
    if (t < Nn * Nn) {
        int i = t >> 8, jx = t & 255;
        float v = sigmoidf_(fmaf(*pw, dis[t], *pb));
        int itile = i >> 4, ln16 = i & 15;
        int k0 = jx >> 5, q = (jx >> 3) & 3, jj = jx & 7;
        DAf[(size_t)((((itile * 8 + k0) << 6) + (q << 4) + ln16)) * 8 + jj] = to_bf16(v);
    }
}

// ---------- generic MFMA embed: Y[r][c] = X[r][:KIN] . W[c][:KIN] + bias[c] ----------
template<int KIN, int K0, int NCOLS>
__global__ __launch_bounds__(256) void k_emb(
    const float* __restrict__ X, const __hip_bfloat16* __restrict__ Bswz,
    const float* __restrict__ bias, __hip_bfloat16* __restrict__ Y)
{
    constexpr int KP = K0 * 32;
    constexpr int TPW = NCOLS / 64;        // col-tiles per wave
    constexpr int OLD = NCOLS + 24;        // out-staging stride
    __shared__ __align__(16) __hip_bfloat16 A_s[4 * K0 * 512];
    __shared__ __align__(16) __hip_bfloat16 O_s[64 * OLD];

    const int row0 = blockIdx.x * 64;
    const int t = threadIdx.x;

    {
        const float4* Xb = (const float4*)(X + (size_t)row0 * KIN);
        constexpr int NV = (64 * KIN) / 4;
        for (int c = t; c < NV; c += 256) {
            float4 v = Xb[c];
            int flat = c * 4;
            #pragma unroll
            for (int e = 0; e < 4; e++) {
                int f = flat + e;
                int row = f / KIN, k = f - row * KIN;
                int mt = row >> 4, ln16 = row & 15;
                int k0 = k >> 5, q = (k >> 3) & 3, j = k & 7;
                float vv = (e == 0) ? v.x : (e == 1) ? v.y : (e == 2) ? v.z : v.w;
                A_s[(((mt * K0 + k0) << 6) + (q << 4) + ln16) * 8 + j] = to_bf16(vv);
            }
        }
        constexpr int PAD = KP - KIN;
        for (int c = t; c < 64 * PAD; c += 256) {
            int row = c / PAD, k = KIN + (c - row * PAD);
            int mt = row >> 4, ln16 = row & 15;
            int k0 = k >> 5, q = (k >> 3) & 3, j = k & 7;
            A_s[(((mt * K0 + k0) << 6) + (q << 4) + ln16) * 8 + j] = to_bf16(0.0f);
        }
    }
    __syncthreads();

    const int wv = t >> 6, lane = t & 63;
    const int q = lane >> 4, ln16 = lane & 15;

    f32x4 acc[4][TPW];
    #pragma unroll
    for (int p = 0; p < TPW; p++) {
        float bv = bias[(wv * TPW + p) * 16 + ln16];
        #pragma unroll
        for (int mt = 0; mt < 4; mt++) acc[mt][p] = (f32x4){bv, bv, bv, bv};
    }

    short8 bw[TPW][K0];
    #pragma unroll
    for (int p = 0; p < TPW; p++)
        #pragma unroll
        for (int k0 = 0; k0 < K0; k0++)
            bw[p][k0] = *(const short8*)(Bswz + ((size_t)((wv * TPW + p) * K0 + k0) << 9) + (lane << 3));

    #pragma unroll
    for (int k0 = 0; k0 < K0; k0++) {
        short8 af[4];
        #pragma unroll
        for (int mt = 0; mt < 4; mt++)
            af[mt] = *(const short8*)(A_s + (((mt * K0 + k0) << 6) + lane) * 8);
        #pragma unroll
        for (int mt = 0; mt < 4; mt++)
            #pragma unroll
            for (int p = 0; p < TPW; p++)
                acc[mt][p] = __builtin_amdgcn_mfma_f32_16x16x32_bf16(af[mt], bw[p][k0], acc[mt][p], 0, 0, 0);
    }

    #pragma unroll
    for (int mt = 0; mt < 4; mt++)
        #pragma unroll
        for (int p = 0; p < TPW; p++) {
            int col = (wv * TPW + p) * 16 + ln16;
            #pragma unroll
            for (int r = 0; r < 4; r++)
                O_s[(mt * 16 + q * 4 + r) * OLD + col] = to_bf16(acc[mt][p][r]);
        }
    __syncthreads();
    constexpr int CH = NCOLS / 8;
    for (int c = t; c < 64 * CH; c += 256) {
        int row = c / CH, ch = c - row * CH;
        *(uint4*)(Y + (size_t)(row0 + row) * NCOLS + ch * 8) =
            *(const uint4*)(O_s + row * OLD + ch * 8);
    }
}

// ---------- self-term GEMM: S = nf @ Wself^T + bias  (f32 out, bias-folded) ----------
__global__ __launch_bounds__(256) void k_self(
    const __hip_bfloat16* __restrict__ nf,   // [B*N][NF] bf16
    const __hip_bfloat16* __restrict__ Wsb,  // [16][4][64][8] frag-order (W[:, 0:128])
    const float* __restrict__ bias,          // [ODIM]
    float* __restrict__ S)                   // [B*N][ODIM] f32
{
    __shared__ __align__(16) __hip_bfloat16 A_s[16 * 512];
    const int row0 = blockIdx.x * 64;
    const int t = threadIdx.x;
    const int wv = t >> 6, lane = t & 63;
    const int q = lane >> 4, ln16 = lane & 15;

    const __hip_bfloat16* rowp = nf + (size_t)(row0 + (wv << 4) + ln16) * NF;
    #pragma unroll
    for (int k0 = 0; k0 < 4; k0++)
        *(uint4*)(A_s + ((wv * 4 + k0) * 64 + lane) * 8) =
            *(const uint4*)(rowp + k0 * 32 + q * 8);
    __syncthreads();

    f32x4 acc[4][4];   // [mt][p], wave wv owns col-tiles wv*4+p
    #pragma unroll
    for (int p = 0; p < 4; p++) {
        float bv = bias[(wv * 4 + p) * 16 + ln16];
        #pragma unroll
        for (int mt = 0; mt < 4; mt++) acc[mt][p] = (f32x4){bv, bv, bv, bv};
    }

    #pragma unroll
    for (int k0 = 0; k0 < 4; k0++) {
        short8 af[4];
        #pragma unroll
        for (int mt = 0; mt < 4; mt++)
            af[mt] = *(const short8*)(A_s + ((mt * 4 + k0) * 64 + lane) * 8);
        #pragma unroll
        for (int p = 0; p < 4; p++) {
            short8 bw = *(const short8*)(Wsb + ((size_t)((wv * 4 + p) * 4 + k0) << 9) + (lane << 3));
            #pragma unroll
            for (int mt = 0; mt < 4; mt++)
                acc[mt][p] = __builtin_amdgcn_mfma_f32_16x16x32_bf16(af[mt], bw, acc[mt][p], 0, 0, 0);
        }
    }

    #pragma unroll
    for (int mt = 0; mt < 4; mt++)
        #pragma unroll
        for (int p = 0; p < 4; p++) {
            int col = (wv * 4 + p) * 16 + ln16;
            #pragma unroll
            for (int r = 0; r < 4; r++)
                S[(size_t)(row0 + mt * 16 + q * 4 + r) * ODIM + col] = acc[mt][p][r];
        }
}

// ---------- conv layer: MFMA, K=192 (self-term factored into S), LDS 24 KB ----------
template<bool PRECOMP>
__global__ __launch_bounds__(256, 4) void k_conv_mfma(
    const __hip_bfloat16* __restrict__ nf_in,   // [B*N][NF] bf16
    const float* __restrict__ edge_fea,         // [B*N*M][OEF] f32  (PRECOMP=false)
    const __hip_bfloat16* __restrict__ ef_bf,   // [B*N*M][EF] bf16  (PRECOMP=true)
    const int*   __restrict__ eidx,             // [B*N][M]
    const float* __restrict__ WeT,              // [OEF][EF] f32     (PRECOMP=false)
    const float* __restrict__ be,               // [EF]              (PRECOMP=false)
    const __hip_bfloat16* __restrict__ Wb,      // [16][K0C][64][8] (W[:,128:320])
    const float* __restrict__ S,                // [B*N][ODIM] f32 (self + bias)
    const float* __restrict__ palpha,
    __hip_bfloat16* __restrict__ nf_out)        // [B*N][NF] bf16
{
    __shared__ __align__(16) __hip_bfloat16 A_s[4 * K0C * 512];   // 24576 B

    const int node0 = blockIdx.x * 4;
    const int b = node0 >> 8;
    const int t = threadIdx.x;
    const int wv = t >> 6, lane = t & 63;
    const int q = lane >> 4, ln16 = lane & 15;
    const int row = (wv << 4) + ln16;                 // this lane's A-tile row

    const int myidx = eidx[node0 * Mm + row];
    const unsigned long long mball = __ballot(eidx[node0 * Mm + lane] >= 0);

    // acc init from S (self-term with bias folded); same value for all 4 rows r
    f32x4 accF[4][2], accC[4][2];
    #pragma unroll
    for (int mt = 0; mt < 4; mt++) {
        const float* Sp = S + (size_t)(node0 + mt) * ODIM;
        #pragma unroll
        for (int p = 0; p < 2; p++) {
            int colF = (2 * wv + p) * 16 + ln16;
            float sF = Sp[colF], sC = Sp[colF + NF];
            accF[mt][p] = (f32x4){sF, sF, sF, sF};
            accC[mt][p] = (f32x4){sC, sC, sC, sC};
        }
    }

    // stage A (fragment order; conflict-free base + lane*16)
    {
        int j = myidx < 0 ? 0 : myidx;
        const __hip_bfloat16* gathp = nf_in + (size_t)((b << 8) + j) * NF;
        #pragma unroll
        for (int k0 = 0; k0 < 4; k0++)
            *(uint4*)(A_s + ((wv * K0C + k0) * 64 + lane) * 8) =
                *(const uint4*)(gathp + k0 * 32 + q * 8);
        if (PRECOMP) {
            const __hip_bfloat16* efp = ef_bf + (size_t)((node0 << 4) + row) * EF;
            #pragma unroll
            for (int k0 = 0; k0 < 2; k0++)
                *(uint4*)(A_s + ((wv * K0C + 4 + k0) * 64 + lane) * 8) =
                    *(const uint4*)(efp + k0 * 32 + q * 8);
        } else {
            for (int c = t; c < 64 * EF; c += 256) {
                int rr = c >> 6, col = c & 63;
                float a = be[col];
                const float* er = edge_fea + (size_t)(node0 * Mm + rr) * OEF;
                #pragma unroll
                for (int i = 0; i < OEF; i++) a = fmaf(er[i], WeT[i * EF + col], a);
                int mt = rr >> 4, l16 = rr & 15;
                int k0 = 4 + (col >> 5), qq = (col >> 3) & 3, jj = col & 7;
                A_s[((mt * K0C + k0) * 64 + qq * 16 + l16) * 8 + jj] = to_bf16(a);
            }
        }
    }
    __syncthreads();

    // B pointers: tile stride = K0C*512 = 3072 elems
    const __hip_bfloat16* WF0 = Wb + ((size_t)(2 * wv) * (K0C * 512)) + (lane << 3);
    const __hip_bfloat16* WF1 = WF0 + K0C * 512;
    const __hip_bfloat16* WC0 = WF0 + 8 * (K0C * 512);
    const __hip_bfloat16* WC1 = WC0 + K0C * 512;

    #pragma unroll
    for (int k0 = 0; k0 < K0C; k0++) {
        short8 cF0 = *(const short8*)(WF0 + k0 * 512);
        short8 cF1 = *(const short8*)(WF1 + k0 * 512);
        short8 cC0 = *(const short8*)(WC0 + k0 * 512);
        short8 cC1 = *(const short8*)(WC1 + k0 * 512);
        short8 af[4];
        #pragma unroll
        for (int mt = 0; mt < 4; mt++)
            af[mt] = *(const short8*)(A_s + ((mt * K0C + k0) * 64 + lane) * 8);
        #pragma unroll
        for (int mt = 0; mt < 4; mt++) {
            accF[mt][0] = __builtin_amdgcn_mfma_f32_16x16x32_bf16(af[mt], cF0, accF[mt][0], 0, 0, 0);
            accF[mt][1] = __builtin_amdgcn_mfma_f32_16x16x32_bf16(af[mt], cF1, accF[mt][1], 0, 0, 0);
            accC[mt][0] = __builtin_amdgcn_mfma_f32_16x16x32_bf16(af[mt], cC0, accC[mt][0], 0, 0, 0);
            accC[mt][1] = __builtin_amdgcn_mfma_f32_16x16x32_bf16(af[mt], cC1, accC[mt][1], 0, 0, 0);
        }
    }

    // epilogue
    const float alpha = *palpha;
    #pragma unroll
    for (int mt = 0; mt < 4; mt++) {
        const int gnode = node0 + mt;
        #pragma unroll
        for (int p = 0; p < 2; p++) {
            float partial = 0.0f;
            #pragma unroll
            for (int r = 0; r < 4; r++) {
                bool msk = (mball >> (mt * 16 + q * 4 + r)) & 1ull;
                float f = sigmoidf_(accF[mt][p][r]);
                float c = softplusf_(accC[mt][p][r]);
                partial += msk ? f * c : 0.0f;
            }
            partial += __shfl_xor(partial, 16);
            partial += __shfl_xor(partial, 32);
            if (q == 0) {
                int col = (2 * wv + p) * 16 + ln16;
                float self = __bfloat162float(nf_in[(size_t)gnode * NF + col]);
                nf_out[(size_t)gnode * NF + col] = to_bf16(softplusf_(fmaf(alpha, self, partial)));
            }
        }
    }
}

// ---------- final linear (MFMA): out[:, :, 0:64] = nf3 @ Wf^T + bf ----------
__global__ __launch_bounds__(256) void k_final_mfma(
    const __hip_bfloat16* __restrict__ nf, const __hip_bfloat16* __restrict__ Wfb,
    const float* __restrict__ bfv, float* __restrict__ out,
    __hip_bfloat16* __restrict__ XT)
{
    __shared__ __align__(16) __hip_bfloat16 A_s[16 * 512];  // 16 KB
    const int node0 = blockIdx.x * 64;
    const int bloc = node0 >> 8;
    const int t = threadIdx.x;
    const int wv = t >> 6, lane = t & 63;
    const int q = lane >> 4, ln16 = lane & 15;

    const __hip_bfloat16* rowp = nf + (size_t)(node0 + (wv << 4) + ln16) * NF;
    #pragma unroll
    for (int k0 = 0; k0 < 4; k0++)
        *(uint4*)(A_s + ((wv * 4 + k0) * 64 + lane) * 8) =
            *(const uint4*)(rowp + k0 * 32 + q * 8);
    __syncthreads();

    short8 bw[4];
    #pragma unroll
    for (int k0 = 0; k0 < 4; k0++)
        bw[k0] = *(const short8*)(Wfb + ((size_t)(wv * 4 + k0) * 64 + lane) * 8);

    float bv = bfv[wv * 16 + ln16];
    f32x4 acc[4];
    #pragma unroll
    for (int mt = 0; mt < 4; mt++) acc[mt] = (f32x4){bv, bv, bv, bv};

    #pragma unroll
    for (int k0 = 0; k0 < 4; k0++) {
        short8 af[4];
        #pragma unroll
        for (int mt = 0; mt < 4; mt++)
            af[mt] = *(const short8*)(A_s + ((mt * 4 + k0) * 64 + lane) * 8);
        #pragma unroll
        for (int mt = 0; mt < 4; mt++)
            acc[mt] = __builtin_amdgcn_mfma_f32_16x16x32_bf16(af[mt], bw[k0], acc[mt], 0, 0, 0);
    }

    const int col = (wv << 4) + ln16;                 // 0..63
    #pragma unroll
    for (int mt = 0; mt < 4; mt++)
        #pragma unroll
        for (int r = 0; r < 4; r++) {
            int row = mt * 16 + q * 4 + r;            // 0..63
            float v = acc[mt][r];
            out[(size_t)(node0 + row) * FINAL + col] = v;
            XT[(size_t)(bloc * 64 + col) * 256 + (node0 & 255) + row] = to_bf16(v);
        }
}

// ---------- node1 (MFMA): out[:, :, 64:128] = DA @ nff per batch ----------
__global__ __launch_bounds__(256) void k_node1_mfma(
    const __hip_bfloat16* __restrict__ DAf,   // A-fragment order [16][8][64][8]
    const __hip_bfloat16* __restrict__ XT,    // [B][64 f][256 j] bf16
    float* __restrict__ out)
{
    __shared__ __align__(16) __hip_bfloat16 B_s[32 * 512];  // 32 KB
    const int blk = blockIdx.x;
    const int b = blk >> 2, i0 = (blk & 3) * 64;
    const int t = threadIdx.x;
    const int wv = t >> 6, lane = t & 63;
    const int q = lane >> 4, ln16 = lane & 15;

    const __hip_bfloat16* xrow = XT + (size_t)(b * 64 + (wv << 4) + ln16) * 256;
    #pragma unroll
    for (int k0 = 0; k0 < 8; k0++)
        *(uint4*)(B_s + ((wv * 8 + k0) * 64 + lane) * 8) =
            *(const uint4*)(xrow + k0 * 32 + q * 8);
    __syncthreads();

    f32x4 acc[4];
    #pragma unroll
    for (int mt = 0; mt < 4; mt++) acc[mt] = (f32x4){0.f, 0.f, 0.f, 0.f};

    #pragma unroll
    for (int k0 = 0; k0 < 8; k0++) {
        short8 bfr = *(const short8*)(B_s + ((wv * 8 + k0) * 64 + lane) * 8);
        short8 af[4];
        #pragma unroll
        for (int mt = 0; mt < 4; mt++)
            af[mt] = *(const short8*)(DAf + (size_t)(((i0 >> 4) + mt) * 8 + k0) * 512 + (lane << 3));
        #pragma unroll
        for (int mt = 0; mt < 4; mt++)
            acc[mt] = __builtin_amdgcn_mfma_f32_16x16x32_bf16(af[mt], bfr, acc[mt], 0, 0, 0);
    }

    #pragma unroll
    for (int mt = 0; mt < 4; mt++)
        #pragma unroll
        for (int r = 0; r < 4; r++) {
            int i = i0 + mt * 16 + q * 4 + r;
            out[(size_t)((b << 8) + i) * FINAL + 64 + (wv << 4) + ln16] = acc[mt][r];
        }
}

extern "C" void kernel_launch(void* const* d_in, const int* in_sizes, int n_in,
                              void* d_out, int out_size, void* d_ws, size_t ws_size,
                              hipStream_t stream)
{
    const float* node_fea = (const float*)d_in[0];
    const float* edge_fea = (const float*)d_in[1];
    const int*   eidx     = (const int*)  d_in[2];
    const float* dis      = (const float*)d_in[3];
    const float* Wn = (const float*)d_in[4];
    const float* bn = (const float*)d_in[5];
    const float* We = (const float*)d_in[6];
    const float* be = (const float*)d_in[7];
    const float* W1 = (const float*)d_in[8];
    const float* b1 = (const float*)d_in[9];
    const float* a1 = (const float*)d_in[10];
    const float* W2 = (const float*)d_in[11];
    const float* b2 = (const float*)d_in[12];
    const float* a2 = (const float*)d_in[13];
    const float* W3 = (const float*)d_in[14];
    const float* b3 = (const float*)d_in[15];
    const float* a3 = (const float*)d_in[16];
    const float* Wf = (const float*)d_in[17];
    const float* bf = (const float*)d_in[18];
    const float* DAw = (const float*)d_in[19];
    const float* DAb = (const float*)d_in[20];
    float* out = (float*)d_out;

    // workspace layout (bytes, 256-aligned blocks)
    char* base = (char*)d_ws;
    size_t off = 0;
    auto alloc = [&](size_t bytes) { char* p = base + off; off = (off + bytes + 255) & ~(size_t)255; return p; };
    __hip_bfloat16* nfA = (__hip_bfloat16*)alloc((size_t)Bb * Nn * NF * 2);
    __hip_bfloat16* nfB = (__hip_bfloat16*)alloc((size_t)Bb * Nn * NF * 2);
    __hip_bfloat16* W1b = (__hip_bfloat16*)alloc((size_t)16 * K0C * 512 * 2);       // conv B (K=192)
    __hip_bfloat16* W2b = (__hip_bfloat16*)alloc((size_t)16 * K0C * 512 * 2);
    __hip_bfloat16* W3b = (__hip_bfloat16*)alloc((size_t)16 * K0C * 512 * 2);
    __hip_bfloat16* W1s = (__hip_bfloat16*)alloc((size_t)16 * 4 * 512 * 2);         // self B (K=128)
    __hip_bfloat16* W2s = (__hip_bfloat16*)alloc((size_t)16 * 4 * 512 * 2);
    __hip_bfloat16* W3s = (__hip_bfloat16*)alloc((size_t)16 * 4 * 512 * 2);
    float* WeT = (float*)alloc((size_t)OEF * EF * 4);                               // fallback conv path
    __hip_bfloat16* DAf = (__hip_bfloat16*)alloc((size_t)Nn * Nn * 2);              // DA, A-frag order
    __hip_bfloat16* Wnb = (__hip_bfloat16*)alloc((size_t)(NF / 16) * 3 * 512 * 2);  // node embed B, K0=3
    __hip_bfloat16* Web = (__hip_bfloat16*)alloc((size_t)(EF / 16) * 2 * 512 * 2);  // edge embed B, K0=2
    __hip_bfloat16* Wfb = (__hip_bfloat16*)alloc((size_t)(64 / 16) * 4 * 512 * 2);  // final B, K0=4
    __hip_bfloat16* XT  = (__hip_bfloat16*)alloc((size_t)Bb * 64 * Nn * 2);         // nff^T per batch
    float* S = (float*)alloc((size_t)Bb * Nn * ODIM * 4);                           // 16 MB self-term
    __hip_bfloat16* efb = (__hip_bfloat16*)alloc((size_t)Bb * Nn * Mm * EF * 2);    // 33.5 MB
    const bool precomp = (ws_size >= off);

    // prep: fragment-order weight swizzles
    hipLaunchKernelGGL(k_transpose, dim3((EF * OEF + 255) / 256), dim3(256), 0, stream, We, WeT, EF, OEF);
    hipLaunchKernelGGL(k_wswz2, dim3((16 * K0C * 512 + 255) / 256), dim3(256), 0, stream, W1, W1b, ODIM, KDIM, NF, 192, K0C);
    hipLaunchKernelGGL(k_wswz2, dim3((16 * K0C * 512 + 255) / 256), dim3(256), 0, stream, W2, W2b, ODIM, KDIM, NF, 192, K0C);
    hipLaunchKernelGGL(k_wswz2, dim3((16 * K0C * 512 + 255) / 256), dim3(256), 0, stream, W3, W3b, ODIM, KDIM, NF, 192, K0C);
    hipLaunchKernelGGL(k_wswz2, dim3((16 * 4 * 512 + 255) / 256), dim3(256), 0, stream, W1, W1s, ODIM, KDIM, 0, NF, 4);
    hipLaunchKernelGGL(k_wswz2, dim3((16 * 4 * 512 + 255) / 256), dim3(256), 0, stream, W2, W2s, ODIM, KDIM, 0, NF, 4);
    hipLaunchKernelGGL(k_wswz2, dim3((16 * 4 * 512 + 255) / 256), dim3(256), 0, stream, W3, W3s, ODIM, KDIM, 0, NF, 4);
    hipLaunchKernelGGL(k_wswz2, dim3((8 * 3 * 512 + 255) / 256), dim3(256), 0, stream, Wn, Wnb, NF, ONF, 0, ONF, 3);
    hipLaunchKernelGGL(k_wswz2, dim3((4 * 2 * 512 + 255) / 256), dim3(256), 0, stream, We, Web, EF, OEF, 0, OEF, 2);
    hipLaunchKernelGGL(k_wswz2, dim3((4 * 4 * 512 + 255) / 256), dim3(256), 0, stream, Wf, Wfb, 64, NF, 0, NF, 4);
    hipLaunchKernelGGL(k_da, dim3((Nn * Nn + 255) / 256), dim3(256), 0, stream, dis, DAw, DAb, DAf);

    // embeds (MFMA)
    if (precomp)
        hipLaunchKernelGGL((k_emb<OEF, 2, EF>), dim3(Bb * Nn * Mm / 64), dim3(256), 0, stream,
                           edge_fea, Web, be, efb);
    hipLaunchKernelGGL((k_emb<ONF, 3, NF>), dim3(Bb * Nn / 64), dim3(256), 0, stream,
                       node_fea, Wnb, bn, nfA);

    const int NG = Bb * Nn / 64;     // 256 blocks for k_self
    if (precomp) {
        hipLaunchKernelGGL(k_self, dim3(NG), dim3(256), 0, stream, nfA, W1s, b1, S);
        hipLaunchKernelGGL((k_conv_mfma<true>), dim3(Bb * Nn / 4), dim3(256), 0, stream,
                           nfA, edge_fea, efb, eidx, WeT, be, W1b, S, a1, nfB);
        hipLaunchKernelGGL(k_self, dim3(NG), dim3(256), 0, stream, nfB, W2s, b2, S);
        hipLaunchKernelGGL((k_conv_mfma<true>), dim3(Bb * Nn / 4), dim3(256), 0, stream,
                           nfB, edge_fea, efb, eidx, WeT, be, W2b, S, a2, nfA);
        hipLaunchKernelGGL(k_self, dim3(NG), dim3(256), 0, stream, nfA, W3s, b3, S);
        hipLaunchKernelGGL((k_conv_mfma<true>), dim3(Bb * Nn / 4), dim3(256), 0, stream,
                           nfA, edge_fea, efb, eidx, WeT, be, W3b, S, a3, nfB);
    } else {
        hipLaunchKernelGGL(k_self, dim3(NG), dim3(256), 0, stream, nfA, W1s, b1, S);
        hipLaunchKernelGGL((k_conv_mfma<false>), dim3(Bb * Nn / 4), dim3(256), 0, stream,
                           nfA, edge_fea, efb, eidx, WeT, be, W1b, S, a1, nfB);
        hipLaunchKernelGGL(k_self, dim3(NG), dim3(256), 0, stream, nfB, W2s, b2, S);
        hipLaunchKernelGGL((k_conv_mfma<false>), dim3(Bb * Nn / 4), dim3(256), 0, stream,
                           nfB, edge_fea, efb, eidx, WeT, be, W2b, S, a2, nfA);
        hipLaunchKernelGGL(k_self, dim3(NG), dim3(256), 0, stream, nfA, W3s, b3, S);
        hipLaunchKernelGGL((k_conv_mfma<false>), dim3(Bb * Nn / 4), dim3(256), 0, stream,
                           nfA, edge_fea, efb, eidx, WeT, be, W3b, S, a3, nfB);
    }

    hipLaunchKernelGGL(k_final_mfma, dim3(Bb * Nn / 64), dim3(256), 0, stream, nfB, Wfb, bf, out, XT);
    hipLaunchKernelGGL(k_node1_mfma, dim3(Bb * 4), dim3(256), 0, stream, DAf, XT, out);
}

// Round 8
// 308.780 us; speedup vs baseline: 1.1880x; 1.1165x over previous
//
#include <hip/hip_runtime.h>
#include <hip/hip_bf16.h>
#include <math.h>

#define Bb   64
#define Nn   256
#define Mm   16
#define ONF  92
#define OEF  41
#define NF   128
#define EF   64
#define KDIM 320   // 2*NF + EF
#define ODIM 256   // 2*NF
#define FINAL 128
#define K0C  6     // conv K-chunks (K=192: gather 128 + edge 64)

typedef __attribute__((ext_vector_type(8))) short short8;
typedef __attribute__((ext_vector_type(4))) float f32x4;

__device__ __forceinline__ float sigmoidf_(float x) {
    float e = __expf(-x);
    return __builtin_amdgcn_rcpf(1.0f + e);
}
__device__ __forceinline__ float softplusf_(float x) {
    return fmaxf(x, 0.0f) + __logf(1.0f + __expf(-fabsf(x)));
}
__device__ __forceinline__ __hip_bfloat16 to_bf16(float x) { return __float2bfloat16(x); }

// ---------- mega-prep: all weight swizzles + WeT + DA in ONE launch ----------
__device__ __forceinline__ void swz(const float* __restrict__ in, __hip_bfloat16* __restrict__ out,
                                    int t, int Itot, int koff, int Kuse, int K0)
{
    int j = t & 7;
    int u = t >> 3;
    int lane = u & 63;
    int ln16 = lane & 15, q = lane >> 4;
    int v = u >> 6;
    int k0 = v % K0, tile = v / K0;
    int n = tile * 16 + ln16, k = k0 * 32 + q * 8 + j;
    out[t] = (k < Kuse) ? to_bf16(in[(size_t)n * Itot + koff + k]) : to_bf16(0.0f);
}

#define SZ_WET (OEF * EF)          // 2624
#define SZ_WB  (16 * K0C * 512)    // 49152
#define SZ_WS  (16 * 4 * 512)      // 32768
#define SZ_WNB ((NF / 16) * 3 * 512)
#define SZ_WEB ((EF / 16) * 2 * 512)
#define SZ_WFB ((64 / 16) * 4 * 512)
#define SZ_DA  (Nn * Nn)
#define PREP_TOTAL (SZ_WET + 3 * SZ_WB + 3 * SZ_WS + SZ_WNB + SZ_WEB + SZ_WFB + SZ_DA)

__global__ __launch_bounds__(256) void k_prep(
    const float* __restrict__ We, const float* __restrict__ W1,
    const float* __restrict__ W2, const float* __restrict__ W3,
    const float* __restrict__ Wn, const float* __restrict__ Wf,
    const float* __restrict__ dis, const float* __restrict__ pw, const float* __restrict__ pb,
    float* __restrict__ WeT,
    __hip_bfloat16* __restrict__ W1b, __hip_bfloat16* __restrict__ W2b, __hip_bfloat16* __restrict__ W3b,
    __hip_bfloat16* __restrict__ W1s, __hip_bfloat16* __restrict__ W2s, __hip_bfloat16* __restrict__ W3s,
    __hip_bfloat16* __restrict__ Wnb, __hip_bfloat16* __restrict__ Web, __hip_bfloat16* __restrict__ Wfb,
    __hip_bfloat16* __restrict__ DAf)
{
    int t = blockIdx.x * 256 + threadIdx.x;
    if (t < SZ_WET) {  // WeT[i][o] = We[o][i], o<EF rows, i<OEF
        int o = t / OEF, i = t - o * OEF;
        WeT[i * EF + o] = We[t];
        return;
    }
    t -= SZ_WET;
    if (t < SZ_WB) { swz(W1, W1b, t, KDIM, NF, 192, K0C); return; }
    t -= SZ_WB;
    if (t < SZ_WB) { swz(W2, W2b, t, KDIM, NF, 192, K0C); return; }
    t -= SZ_WB;
    if (t < SZ_WB) { swz(W3, W3b, t, KDIM, NF, 192, K0C); return; }
    t -= SZ_WB;
    if (t < SZ_WS) { swz(W1, W1s, t, KDIM, 0, NF, 4); return; }
    t -= SZ_WS;
    if (t < SZ_WS) { swz(W2, W2s, t, KDIM, 0, NF, 4); return; }
    t -= SZ_WS;
    if (t < SZ_WS) { swz(W3, W3s, t, KDIM, 0, NF, 4); return; }
    t -= SZ_WS;
    if (t < SZ_WNB) { swz(Wn, Wnb, t, ONF, 0, ONF, 3); return; }
    t -= SZ_WNB;
    if (t < SZ_WEB) { swz(We, Web, t, OEF, 0, OEF, 2); return; }
    t -= SZ_WEB;
    if (t < SZ_WFB) { swz(Wf, Wfb, t, NF, 0, NF, 4); return; }
    t -= SZ_WFB;
    if (t < SZ_DA) {
        int i = t >> 8, jx = t & 255;
        float v = sigmoidf_(fmaf(*pw, dis[t], *pb));
        int itile = i >> 4, ln16 = i & 15;
        int k0 = jx >> 5, q = (jx >> 3) & 3, jj = jx & 7;
        DAf[(size_t)((((itile * 8 + k0) << 6) + (q << 4) + ln16)) * 8 + jj] = to_bf16(v);
    }
}

// ---------- generic MFMA embed body ----------
template<int KIN, int K0, int NCOLS>
__device__ __forceinline__ void emb_body(
    int bid, const float* __restrict__ X, const __hip_bfloat16* __restrict__ Bswz,
    const float* __restrict__ bias, __hip_bfloat16* __restrict__ Y,
    __hip_bfloat16* A_s, __hip_bfloat16* O_s)
{
    constexpr int KP = K0 * 32;
    constexpr int TPW = NCOLS / 64;
    constexpr int OLD = NCOLS + 24;

    const int row0 = bid * 64;
    const int t = threadIdx.x;

    {
        const float4* Xb = (const float4*)(X + (size_t)row0 * KIN);
        constexpr int NV = (64 * KIN) / 4;
        for (int c = t; c < NV; c += 256) {
            float4 v = Xb[c];
            int flat = c * 4;
            #pragma unroll
            for (int e = 0; e < 4; e++) {
                int f = flat + e;
                int row = f / KIN, k = f - row * KIN;
                int mt = row >> 4, ln16 = row & 15;
                int k0 = k >> 5, q = (k >> 3) & 3, j = k & 7;
                float vv = (e == 0) ? v.x : (e == 1) ? v.y : (e == 2) ? v.z : v.w;
                A_s[(((mt * K0 + k0) << 6) + (q << 4) + ln16) * 8 + j] = to_bf16(vv);
            }
        }
        constexpr int PAD = KP - KIN;
        for (int c = t; c < 64 * PAD; c += 256) {
            int row = c / PAD, k = KIN + (c - row * PAD);
            int mt = row >> 4, ln16 = row & 15;
            int k0 = k >> 5, q = (k >> 3) & 3, j = k & 7;
            A_s[(((mt * K0 + k0) << 6) + (q << 4) + ln16) * 8 + j] = to_bf16(0.0f);
        }
    }
    __syncthreads();

    const int wv = t >> 6, lane = t & 63;
    const int q = lane >> 4, ln16 = lane & 15;

    f32x4 acc[4][TPW];
    #pragma unroll
    for (int p = 0; p < TPW; p++) {
        float bv = bias[(wv * TPW + p) * 16 + ln16];
        #pragma unroll
        for (int mt = 0; mt < 4; mt++) acc[mt][p] = (f32x4){bv, bv, bv, bv};
    }

    short8 bw[TPW][K0];
    #pragma unroll
    for (int p = 0; p < TPW; p++)
        #pragma unroll
        for (int k0 = 0; k0 < K0; k0++)
            bw[p][k0] = *(const short8*)(Bswz + ((size_t)((wv * TPW + p) * K0 + k0) << 9) + (lane << 3));

    #pragma unroll
    for (int k0 = 0; k0 < K0; k0++) {
        short8 af[4];
        #pragma unroll
        for (int mt = 0; mt < 4; mt++)
            af[mt] = *(const short8*)(A_s + (((mt * K0 + k0) << 6) + lane) * 8);
        #pragma unroll
        for (int mt = 0; mt < 4; mt++)
            #pragma unroll
            for (int p = 0; p < TPW; p++)
                acc[mt][p] = __builtin_amdgcn_mfma_f32_16x16x32_bf16(af[mt], bw[p][k0], acc[mt][p], 0, 0, 0);
    }

    #pragma unroll
    for (int mt = 0; mt < 4; mt++)
        #pragma unroll
        for (int p = 0; p < TPW; p++) {
            int col = (wv * TPW + p) * 16 + ln16;
            #pragma unroll
            for (int r = 0; r < 4; r++)
                O_s[(mt * 16 + q * 4 + r) * OLD + col] = to_bf16(acc[mt][p][r]);
        }
    __syncthreads();
    constexpr int CH = NCOLS / 8;
    for (int c = t; c < 64 * CH; c += 256) {
        int row = c / CH, ch = c - row * CH;
        *(uint4*)(Y + (size_t)(row0 + row) * NCOLS + ch * 8) =
            *(const uint4*)(O_s + row * OLD + ch * 8);
    }
}

// blocks [0,256): node embed; [256, 256+4096): edge embed
__global__ __launch_bounds__(256) void k_embed_all(
    const float* __restrict__ node_fea, const __hip_bfloat16* __restrict__ Wnb,
    const float* __restrict__ bn, __hip_bfloat16* __restrict__ nf0,
    const float* __restrict__ edge_fea, const __hip_bfloat16* __restrict__ Web,
    const float* __restrict__ be, __hip_bfloat16* __restrict__ efb)
{
    __shared__ __align__(16) __hip_bfloat16 A_s[4 * 3 * 512];        // max K0=3
    __shared__ __align__(16) __hip_bfloat16 O_s[64 * (NF + 24)];     // max NCOLS=128
    if (blockIdx.x < 256)
        emb_body<ONF, 3, NF>(blockIdx.x, node_fea, Wnb, bn, nf0, A_s, O_s);
    else
        emb_body<OEF, 2, EF>(blockIdx.x - 256, edge_fea, Web, be, efb, A_s, O_s);
}

// ---------- conv layer: MFMA, K=192, self-term fused via in-kernel MFMA ----------
template<bool PRECOMP>
__global__ __launch_bounds__(256, 3) void k_conv_mfma(
    const __hip_bfloat16* __restrict__ nf_in,   // [B*N][NF] bf16
    const float* __restrict__ edge_fea,         // [B*N*M][OEF] f32  (PRECOMP=false)
    const __hip_bfloat16* __restrict__ ef_bf,   // [B*N*M][EF] bf16  (PRECOMP=true)
    const int*   __restrict__ eidx,             // [B*N][M]
    const float* __restrict__ WeT,              // [OEF][EF] f32     (PRECOMP=false)
    const float* __restrict__ be,               // [EF]              (PRECOMP=false)
    const __hip_bfloat16* __restrict__ Wb,      // [16][K0C][64][8] (W[:,128:320])
    const __hip_bfloat16* __restrict__ Wsb,     // [16][4][64][8]   (W[:,0:128])
    const float* __restrict__ bias,             // [ODIM]
    const float* __restrict__ palpha,
    __hip_bfloat16* __restrict__ nf_out)        // [B*N][NF] bf16
{
    __shared__ __align__(16) __hip_bfloat16 A_s[4 * K0C * 512];   // 24576 B
    __shared__ __align__(16) __hip_bfloat16 A_sf[4 * 512];        //  4096 B (self rows 0..3)

    const int node0 = blockIdx.x * 4;
    const int b = node0 >> 8;
    const int t = threadIdx.x;
    const int wv = t >> 6, lane = t & 63;
    const int q = lane >> 4, ln16 = lane & 15;
    const int row = (wv << 4) + ln16;                 // this lane's A-tile row

    const int myidx = eidx[node0 * Mm + row];
    const unsigned long long mball = __ballot(eidx[node0 * Mm + lane] >= 0);

    // stage A (fragment order; conflict-free base + lane*16)
    {
        int j = myidx < 0 ? 0 : myidx;
        const __hip_bfloat16* gathp = nf_in + (size_t)((b << 8) + j) * NF;
        #pragma unroll
        for (int k0 = 0; k0 < 4; k0++)
            *(uint4*)(A_s + ((wv * K0C + k0) * 64 + lane) * 8) =
                *(const uint4*)(gathp + k0 * 32 + q * 8);
        // self rows: wave wv stages node wv's row (lanes 0..15, chunk=lane)
        if (lane < 16)
            *(uint4*)(A_sf + (((lane >> 2) * 64) + (lane & 3) * 16 + wv) * 8) =
                *(const uint4*)(nf_in + (size_t)(node0 + wv) * NF + lane * 8);
        if (PRECOMP) {
            const __hip_bfloat16* efp = ef_bf + (size_t)((node0 << 4) + row) * EF;
            #pragma unroll
            for (int k0 = 0; k0 < 2; k0++)
                *(uint4*)(A_s + ((wv * K0C + 4 + k0) * 64 + lane) * 8) =
                    *(const uint4*)(efp + k0 * 32 + q * 8);
        } else {
            for (int c = t; c < 64 * EF; c += 256) {
                int rr = c >> 6, col = c & 63;
                float a = be[col];
                const float* er = edge_fea + (size_t)(node0 * Mm + rr) * OEF;
                #pragma unroll
                for (int i = 0; i < OEF; i++) a = fmaf(er[i], WeT[i * EF + col], a);
                int mt = rr >> 4, l16 = rr & 15;
                int k0 = 4 + (col >> 5), qq = (col >> 3) & 3, jj = col & 7;
                A_s[((mt * K0C + k0) * 64 + qq * 16 + l16) * 8 + jj] = to_bf16(a);
            }
        }
    }
    __syncthreads();

    // ---- self-term S via MFMA (C rows 0..3 hold S[node 0..3]; rows 4..15 garbage, unused)
    // tiles this wave needs: F: 2wv, 2wv+1 ; C: 2wv+8, 2wv+9
    f32x4 sv[4];
    #pragma unroll
    for (int c = 0; c < 4; c++) {
        int tile = 2 * wv + (c & 1) + ((c >> 1) << 3);
        float bv = bias[tile * 16 + ln16];
        sv[c] = (f32x4){bv, bv, bv, bv};
    }
    #pragma unroll
    for (int k0 = 0; k0 < 4; k0++) {
        short8 afs = *(const short8*)(A_sf + (k0 * 64 + lane) * 8);
        #pragma unroll
        for (int c = 0; c < 4; c++) {
            int tile = 2 * wv + (c & 1) + ((c >> 1) << 3);
            short8 bws = *(const short8*)(Wsb + ((size_t)(tile * 4 + k0) << 9) + (lane << 3));
            sv[c] = __builtin_amdgcn_mfma_f32_16x16x32_bf16(afs, bws, sv[c], 0, 0, 0);
        }
    }

    // broadcast S[mt][col] (held at lane ln16, q=0, reg mt) to all lanes -> acc init
    f32x4 accF[4][2], accC[4][2];
    #pragma unroll
    for (int mt = 0; mt < 4; mt++) {
        #pragma unroll
        for (int p = 0; p < 2; p++) {
            float vF = __shfl(sv[p][mt], ln16);
            float vC = __shfl(sv[2 + p][mt], ln16);
            accF[mt][p] = (f32x4){vF, vF, vF, vF};
            accC[mt][p] = (f32x4){vC, vC, vC, vC};
        }
    }

    // ---- main K-loop (K=192): gather + edge
    const __hip_bfloat16* WF0 = Wb + ((size_t)(2 * wv) * (K0C * 512)) + (lane << 3);
    const __hip_bfloat16* WF1 = WF0 + K0C * 512;
    const __hip_bfloat16* WC0 = WF0 + 8 * (K0C * 512);
    const __hip_bfloat16* WC1 = WC0 + K0C * 512;

    #pragma unroll
    for (int k0 = 0; k0 < K0C; k0++) {
        short8 cF0 = *(const short8*)(WF0 + k0 * 512);
        short8 cF1 = *(const short8*)(WF1 + k0 * 512);
        short8 cC0 = *(const short8*)(WC0 + k0 * 512);
        short8 cC1 = *(const short8*)(WC1 + k0 * 512);
        short8 af[4];
        #pragma unroll
        for (int mt = 0; mt < 4; mt++)
            af[mt] = *(const short8*)(A_s + ((mt * K0C + k0) * 64 + lane) * 8);
        #pragma unroll
        for (int mt = 0; mt < 4; mt++) {
            accF[mt][0] = __builtin_amdgcn_mfma_f32_16x16x32_bf16(af[mt], cF0, accF[mt][0], 0, 0, 0);
            accF[mt][1] = __builtin_amdgcn_mfma_f32_16x16x32_bf16(af[mt], cF1, accF[mt][1], 0, 0, 0);
            accC[mt][0] = __builtin_amdgcn_mfma_f32_16x16x32_bf16(af[mt], cC0, accC[mt][0], 0, 0, 0);
            accC[mt][1] = __builtin_amdgcn_mfma_f32_16x16x32_bf16(af[mt], cC1, accC[mt][1], 0, 0, 0);
        }
    }

    // epilogue
    const float alpha = *palpha;
    #pragma unroll
    for (int mt = 0; mt < 4; mt++) {
        const int gnode = node0 + mt;
        #pragma unroll
        for (int p = 0; p < 2; p++) {
            float partial = 0.0f;
            #pragma unroll
            for (int r = 0; r < 4; r++) {
                bool msk = (mball >> (mt * 16 + q * 4 + r)) & 1ull;
                float f = sigmoidf_(accF[mt][p][r]);
                float c = softplusf_(accC[mt][p][r]);
                partial += msk ? f * c : 0.0f;
            }
            partial += __shfl_xor(partial, 16);
            partial += __shfl_xor(partial, 32);
            if (q == 0) {
                int col = (2 * wv + p) * 16 + ln16;
                float self = __bfloat162float(nf_in[(size_t)gnode * NF + col]);
                nf_out[(size_t)gnode * NF + col] = to_bf16(softplusf_(fmaf(alpha, self, partial)));
            }
        }
    }
}

// ---------- final linear (MFMA): out[:, :, 0:64] = nf3 @ Wf^T + bf ----------
__global__ __launch_bounds__(256) void k_final_mfma(
    const __hip_bfloat16* __restrict__ nf, const __hip_bfloat16* __restrict__ Wfb,
    const float* __restrict__ bfv, float* __restrict__ out,
    __hip_bfloat16* __restrict__ XT)
{
    __shared__ __align__(16) __hip_bfloat16 A_s[16 * 512];  // 16 KB
    const int node0 = blockIdx.x * 64;
    const int bloc = node0 >> 8;
    const int t = threadIdx.x;
    const int wv = t >> 6, lane = t & 63;
    const int q = lane >> 4, ln16 = lane & 15;

    const __hip_bfloat16* rowp = nf + (size_t)(node0 + (wv << 4) + ln16) * NF;
    #pragma unroll
    for (int k0 = 0; k0 < 4; k0++)
        *(uint4*)(A_s + ((wv * 4 + k0) * 64 + lane) * 8) =
            *(const uint4*)(rowp + k0 * 32 + q * 8);
    __syncthreads();

    short8 bw[4];
    #pragma unroll
    for (int k0 = 0; k0 < 4; k0++)
        bw[k0] = *(const short8*)(Wfb + ((size_t)(wv * 4 + k0) * 64 + lane) * 8);

    float bv = bfv[wv * 16 + ln16];
    f32x4 acc[4];
    #pragma unroll
    for (int mt = 0; mt < 4; mt++) acc[mt] = (f32x4){bv, bv, bv, bv};

    #pragma unroll
    for (int k0 = 0; k0 < 4; k0++) {
        short8 af[4];
        #pragma unroll
        for (int mt = 0; mt < 4; mt++)
            af[mt] = *(const short8*)(A_s + ((mt * 4 + k0) * 64 + lane) * 8);
        #pragma unroll
        for (int mt = 0; mt < 4; mt++)
            acc[mt] = __builtin_amdgcn_mfma_f32_16x16x32_bf16(af[mt], bw[k0], acc[mt], 0, 0, 0);
    }

    const int col = (wv << 4) + ln16;                 // 0..63
    #pragma unroll
    for (int mt = 0; mt < 4; mt++)
        #pragma unroll
        for (int r = 0; r < 4; r++) {
            int row = mt * 16 + q * 4 + r;            // 0..63
            float v = acc[mt][r];
            out[(size_t)(node0 + row) * FINAL + col] = v;
            XT[(size_t)(bloc * 64 + col) * 256 + (node0 & 255) + row] = to_bf16(v);
        }
}

// ---------- node1 (MFMA): out[:, :, 64:128] = DA @ nff per batch ----------
__global__ __launch_bounds__(256) void k_node1_mfma(
    const __hip_bfloat16* __restrict__ DAf,   // A-fragment order [16][8][64][8]
    const __hip_bfloat16* __restrict__ XT,    // [B][64 f][256 j] bf16
    float* __restrict__ out)
{
    __shared__ __align__(16) __hip_bfloat16 B_s[32 * 512];  // 32 KB
    const int blk = blockIdx.x;
    const int b = blk >> 2, i0 = (blk & 3) * 64;
    const int t = threadIdx.x;
    const int wv = t >> 6, lane = t & 63;
    const int q = lane >> 4, ln16 = lane & 15;

    const __hip_bfloat16* xrow = XT + (size_t)(b * 64 + (wv << 4) + ln16) * 256;
    #pragma unroll
    for (int k0 = 0; k0 < 8; k0++)
        *(uint4*)(B_s + ((wv * 8 + k0) * 64 + lane) * 8) =
            *(const uint4*)(xrow + k0 * 32 + q * 8);
    __syncthreads();

    f32x4 acc[4];
    #pragma unroll
    for (int mt = 0; mt < 4; mt++) acc[mt] = (f32x4){0.f, 0.f, 0.f, 0.f};

    #pragma unroll
    for (int k0 = 0; k0 < 8; k0++) {
        short8 bfr = *(const short8*)(B_s + ((wv * 8 + k0) * 64 + lane) * 8);
        short8 af[4];
        #pragma unroll
        for (int mt = 0; mt < 4; mt++)
            af[mt] = *(const short8*)(DAf + (size_t)(((i0 >> 4) + mt) * 8 + k0) * 512 + (lane << 3));
        #pragma unroll
        for (int mt = 0; mt < 4; mt++)
            acc[mt] = __builtin_amdgcn_mfma_f32_16x16x32_bf16(af[mt], bfr, acc[mt], 0, 0, 0);
    }

    #pragma unroll
    for (int mt = 0; mt < 4; mt++)
        #pragma unroll
        for (int r = 0; r < 4; r++) {
            int i = i0 + mt * 16 + q * 4 + r;
            out[(size_t)((b << 8) + i) * FINAL + 64 + (wv << 4) + ln16] = acc[mt][r];
        }
}

extern "C" void kernel_launch(void* const* d_in, const int* in_sizes, int n_in,
                              void* d_out, int out_size, void* d_ws, size_t ws_size,
                              hipStream_t stream)
{
    const float* node_fea = (const float*)d_in[0];
    const float* edge_fea = (const float*)d_in[1];
    const int*   eidx     = (const int*)  d_in[2];
    const float* dis      = (const float*)d_in[3];
    const float* Wn = (const float*)d_in[4];
    const float* bn = (const float*)d_in[5];
    const float* We = (const float*)d_in[6];
    const float* be = (const float*)d_in[7];
    const float* W1 = (const float*)d_in[8];
    const float* b1 = (const float*)d_in[9];
    const float* a1 = (const float*)d_in[10];
    const float* W2 = (const float*)d_in[11];
    const float* b2 = (const float*)d_in[12];
    const float* a2 = (const float*)d_in[13];
    const float* W3 = (const float*)d_in[14];
    const float* b3 = (const float*)d_in[15];
    const float* a3 = (const float*)d_in[16];
    const float* Wf = (const float*)d_in[17];
    const float* bf = (const float*)d_in[18];
    const float* DAw = (const float*)d_in[19];
    const float* DAb = (const float*)d_in[20];
    float* out = (float*)d_out;

    // workspace layout (bytes, 256-aligned blocks)
    char* base = (char*)d_ws;
    size_t off = 0;
    auto alloc = [&](size_t bytes) { char* p = base + off; off = (off + bytes + 255) & ~(size_t)255; return p; };
    __hip_bfloat16* nfA = (__hip_bfloat16*)alloc((size_t)Bb * Nn * NF * 2);
    __hip_bfloat16* nfB = (__hip_bfloat16*)alloc((size_t)Bb * Nn * NF * 2);
    __hip_bfloat16* W1b = (__hip_bfloat16*)alloc((size_t)SZ_WB * 2);
    __hip_bfloat16* W2b = (__hip_bfloat16*)alloc((size_t)SZ_WB * 2);
    __hip_bfloat16* W3b = (__hip_bfloat16*)alloc((size_t)SZ_WB * 2);
    __hip_bfloat16* W1s = (__hip_bfloat16*)alloc((size_t)SZ_WS * 2);
    __hip_bfloat16* W2s = (__hip_bfloat16*)alloc((size_t)SZ_WS * 2);
    __hip_bfloat16* W3s = (__hip_bfloat16*)alloc((size_t)SZ_WS * 2);
    float* WeT = (float*)alloc((size_t)OEF * EF * 4);                               // fallback conv path
    __hip_bfloat16* DAf = (__hip_bfloat16*)alloc((size_t)Nn * Nn * 2);
    __hip_bfloat16* Wnb = (__hip_bfloat16*)alloc((size_t)SZ_WNB * 2);
    __hip_bfloat16* Web = (__hip_bfloat16*)alloc((size_t)SZ_WEB * 2);
    __hip_bfloat16* Wfb = (__hip_bfloat16*)alloc((size_t)SZ_WFB * 2);
    __hip_bfloat16* XT  = (__hip_bfloat16*)alloc((size_t)Bb * 64 * Nn * 2);
    __hip_bfloat16* efb = (__hip_bfloat16*)alloc((size_t)Bb * Nn * Mm * EF * 2);    // 33.5 MB
    const bool precomp = (ws_size >= off);

    // 1 launch: all prep
    hipLaunchKernelGGL(k_prep, dim3((PREP_TOTAL + 255) / 256), dim3(256), 0, stream,
                       We, W1, W2, W3, Wn, Wf, dis, DAw, DAb,
                       WeT, W1b, W2b, W3b, W1s, W2s, W3s, Wnb, Web, Wfb, DAf);

    // 1 launch: both embeds
    hipLaunchKernelGGL(k_embed_all, dim3(precomp ? (256 + Bb * Nn * Mm / 64) : 256), dim3(256), 0, stream,
                       node_fea, Wnb, bn, nfA, edge_fea, Web, be, efb);

    if (precomp) {
        hipLaunchKernelGGL((k_conv_mfma<true>), dim3(Bb * Nn / 4), dim3(256), 0, stream,
                           nfA, edge_fea, efb, eidx, WeT, be, W1b, W1s, b1, a1, nfB);
        hipLaunchKernelGGL((k_conv_mfma<true>), dim3(Bb * Nn / 4), dim3(256), 0, stream,
                           nfB, edge_fea, efb, eidx, WeT, be, W2b, W2s, b2, a2, nfA);
        hipLaunchKernelGGL((k_conv_mfma<true>), dim3(Bb * Nn / 4), dim3(256), 0, stream,
                           nfA, edge_fea, efb, eidx, WeT, be, W3b, W3s, b3, a3, nfB);
    } else {
        hipLaunchKernelGGL((k_conv_mfma<false>), dim3(Bb * Nn / 4), dim3(256), 0, stream,
                           nfA, edge_fea, efb, eidx, WeT, be, W1b, W1s, b1, a1, nfB);
        hipLaunchKernelGGL((k_conv_mfma<false>), dim3(Bb * Nn / 4), dim3(256), 0, stream,
                           nfB, edge_fea, efb, eidx, WeT, be, W2b, W2s, b2, a2, nfA);
        hipLaunchKernelGGL((k_conv_mfma<false>), dim3(Bb * Nn / 4), dim3(256), 0, stream,
                           nfA, edge_fea, efb, eidx, WeT, be, W3b, W3s, b3, a3, nfB);
    }

    hipLaunchKernelGGL(k_final_mfma, dim3(Bb * Nn / 64), dim3(256), 0, stream, nfB, Wfb, bf, out, XT);
    hipLaunchKernelGGL(k_node1_mfma, dim3(Bb * 4), dim3(256), 0, stream, DAf, XT, out);
}